// Round 7
// baseline (502.919 us; speedup 1.0000x reference)
//
#include <hip/hip_runtime.h>

#define R_NODES 100000
#define I_DIM 512
#define K_SEL 512

// ---- workspace layout (bytes) ----
#define OFF_NORM   0                                   // 1 float
#define OFF_GHIST  256                                 // 2048 uint = 8192 B
#define OFF_KEYS   8704                                // 100000 uint = 400000 B
#define OFF_SELIDX 408832                              // 512 int
#define OFF_SELW   410880                              // 512 float
#define OFF_X      413696                              // 512*512 f32 = 1 MB
#define OFF_U      (OFF_X + I_DIM * I_DIM * 4)         // 1 MB
#define OFF_RH     (OFF_U + I_DIM * I_DIM * 4)         // 1 MB
// total ~3.4 MB

__device__ __forceinline__ float sigf(float x) { return 1.0f / (1.0f + __expf(-x)); }

// ---- kernel 0: scorer norm + zero global histogram ----
__global__ __launch_bounds__(256) void k_norm(const float* __restrict__ scorer,
                                              float* __restrict__ inv_norm,
                                              unsigned int* __restrict__ ghist) {
  __shared__ float red[256];
  int t = threadIdx.x;
  for (int b = t; b < 2048; b += 256) ghist[b] = 0u;
  float v0 = scorer[t], v1 = scorer[t + 256];
  red[t] = v0 * v0 + v1 * v1;
  __syncthreads();
  for (int s = 128; s > 0; s >>= 1) {
    if (t < s) red[t] += red[t + s];
    __syncthreads();
  }
  if (t == 0) inv_norm[0] = 1.0f / (sqrtf(red[0]) + 1e-12f);
}

// ---- kernel 1: scores -> sortable keys. one wave per row ----
__global__ __launch_bounds__(256) void k_scores(const float* __restrict__ inputs,
                                                const float* __restrict__ scorer,
                                                const float* __restrict__ mask,
                                                const float* __restrict__ inv_norm,
                                                unsigned int* __restrict__ keys) {
  const int wave = threadIdx.x >> 6;
  const int lane = threadIdx.x & 63;
  const int row = blockIdx.x * 4 + wave;
  const float4* rp = (const float4*)(inputs + (size_t)row * I_DIM);
  const float4* sp = (const float4*)scorer;
  float4 a0 = rp[lane], a1 = rp[lane + 64];
  float4 s0 = sp[lane], s1 = sp[lane + 64];
  float dot = a0.x * s0.x + a0.y * s0.y + a0.z * s0.z + a0.w * s0.w
            + a1.x * s1.x + a1.y * s1.y + a1.z * s1.z + a1.w * s1.w;
#pragma unroll
  for (int off = 32; off >= 1; off >>= 1) dot += __shfl_down(dot, off);
  if (lane == 0) {
    float score = dot * inv_norm[0] + mask[row];
    unsigned int u = __float_as_uint(score);
    keys[row] = (u & 0x80000000u) ? ~u : (u | 0x80000000u);
  }
}

// ---- kernel 2: grid-wide histogram of top 11 key bits ----
__global__ __launch_bounds__(256) void k_hist1(const unsigned int* __restrict__ keys,
                                               unsigned int* __restrict__ ghist) {
  __shared__ unsigned int h[2048];
  int t = threadIdx.x;
  for (int b = t; b < 2048; b += 256) h[b] = 0u;
  __syncthreads();
  int per = (R_NODES + gridDim.x - 1) / gridDim.x;
  int start = blockIdx.x * per;
  int end = start + per;
  if (end > R_NODES) end = R_NODES;
  for (int r = start + t; r < end; r += 256) atomicAdd(&h[keys[r] >> 21], 1u);
  __syncthreads();
  for (int b = t; b < 2048; b += 256) {
    unsigned int v = h[b];
    if (v) atomicAdd(&ghist[b], v);
  }
}

// ---- kernel 3: radix refine + compact + bitonic sort -> sel_idx, sel_w ----
#define SUFFIX_SCAN()                                                         \
  for (int off = 1; off < 2048; off <<= 1) {                                  \
    unsigned int v0 = (t + off < 2048) ? hist[t + off] : 0u;                  \
    unsigned int v1 = (t + 1024 + off < 2048) ? hist[t + 1024 + off] : 0u;    \
    __syncthreads();                                                          \
    hist[t] += v0;                                                            \
    hist[t + 1024] += v1;                                                     \
    __syncthreads();                                                          \
  }

#define FIND_BIN(needv)                                                       \
  {                                                                           \
    for (int q = 0; q < 2; ++q) {                                             \
      int b = t + q * 1024;                                                   \
      unsigned int s_here = hist[b];                                          \
      unsigned int s_next = (b < 2047) ? hist[b + 1] : 0u;                    \
      if (s_here >= (needv) && s_next < (needv)) {                            \
        sh_bin = (unsigned int)b;                                             \
        sh_above = s_next;                                                    \
      }                                                                       \
    }                                                                         \
    __syncthreads();                                                          \
  }

__global__ __launch_bounds__(1024) void k_select(const unsigned int* __restrict__ keys,
                                                 const unsigned int* __restrict__ ghist,
                                                 int* __restrict__ sel_idx,
                                                 float* __restrict__ sel_w) {
  __shared__ unsigned int hist[2048];
  __shared__ unsigned long long cand[2048];
  __shared__ unsigned int sh_bin, sh_above, sh_cnt;
  const int t = threadIdx.x;

  unsigned int need = K_SEL;
  hist[t] = ghist[t];
  hist[t + 1024] = ghist[t + 1024];
  __syncthreads();
  SUFFIX_SCAN();
  FIND_BIN(need);
  unsigned int b1 = sh_bin;
  need -= sh_above;
  __syncthreads();

  // pass 2: next 11 bits within bin b1
  hist[t] = 0u;
  hist[t + 1024] = 0u;
  __syncthreads();
  for (int r = t; r < R_NODES; r += 1024) {
    unsigned int k2 = keys[r];
    if ((k2 >> 21) == b1) atomicAdd(&hist[(k2 >> 10) & 0x7FFu], 1u);
  }
  __syncthreads();
  SUFFIX_SCAN();
  FIND_BIN(need);
  unsigned int b2 = sh_bin;
  unsigned int T = ((b1 << 11) | b2) << 10;  // 22-bit threshold, low bits zero

  // compact all keys >= T (expected ~512-530 candidates)
  if (t == 0) sh_cnt = 0u;
  __syncthreads();
  for (int r = t; r < R_NODES; r += 1024) {
    unsigned int k2 = keys[r];
    if (k2 >= T) {
      unsigned int p = atomicAdd(&sh_cnt, 1u);
      if (p < 2048u)
        cand[p] = ((unsigned long long)k2 << 32) |
                  (unsigned long long)(0xFFFFFFFFu - (unsigned int)r);
    }
  }
  __syncthreads();
  unsigned int cnt = sh_cnt > 2048u ? 2048u : sh_cnt;
  for (int p = t; p < 2048; p += 1024)
    if ((unsigned int)p >= cnt) cand[p] = 0ULL;
  __syncthreads();

  // bitonic ascending sort of 2048 composites (key, ~idx)
  for (int ks = 2; ks <= 2048; ks <<= 1) {
    for (int js = ks >> 1; js > 0; js >>= 1) {
      for (int i = t; i < 2048; i += 1024) {
        int ixj = i ^ js;
        if (ixj > i) {
          unsigned long long x = cand[i], y = cand[ixj];
          bool up = ((i & ks) == 0);
          if (up ? (x > y) : (x < y)) {
            cand[i] = y;
            cand[ixj] = x;
          }
        }
      }
      __syncthreads();
    }
  }

  // top 512 = largest composites, read from the tail (desc key, asc idx on ties)
  for (int j = t; j < K_SEL; j += 1024) {
    unsigned long long c = cand[2047 - j];
    unsigned int key = (unsigned int)(c >> 32);
    unsigned int ridx = 0xFFFFFFFFu - (unsigned int)(c & 0xFFFFFFFFull);
    unsigned int ub = (key & 0x80000000u) ? (key ^ 0x80000000u) : ~key;
    float val = __uint_as_float(ub);
    sel_idx[j] = (int)ridx;
    sel_w[j] = tanhf(val);
  }
}

// ---- kernel 4: X[k][j] = inputs[idx_j][k] * w_j (gather + transpose via LDS) ----
__global__ __launch_bounds__(256) void k_build_x(const float* __restrict__ inputs,
                                                 const int* __restrict__ sel_idx,
                                                 const float* __restrict__ sel_w,
                                                 float* __restrict__ X) {
  __shared__ float tile[32][33];
  const int tx = threadIdx.x;  // 0..31
  const int ty = threadIdx.y;  // 0..7
  const int j0 = blockIdx.x * 32;
  const int k0 = blockIdx.y * 32;
#pragma unroll
  for (int q = 0; q < 4; ++q) {
    int jr = ty + q * 8;
    int j = j0 + jr;
    int row = sel_idx[j];
    float w = sel_w[j];
    tile[jr][tx] = inputs[(size_t)row * I_DIM + k0 + tx] * w;
  }
  __syncthreads();
#pragma unroll
  for (int q = 0; q < 4; ++q) {
    int kk = ty + q * 8;
    X[(k0 + kk) * I_DIM + j0 + tx] = tile[tx][kk];
  }
}

// ---- kernel 5: u = sigmoid(Wu X + Uu H + bu); rh = sigmoid(Wr X + Ur H + br) * H ----
__global__ __launch_bounds__(256) void k_gates(
    const float* __restrict__ Wu, const float* __restrict__ Uu, const float* __restrict__ bu,
    const float* __restrict__ Wr, const float* __restrict__ Ur, const float* __restrict__ br,
    const float* __restrict__ X, const float* __restrict__ H,
    float* __restrict__ ubuf, float* __restrict__ rhbuf) {
  const float* A1 = blockIdx.z ? Wr : Wu;
  const float* A2 = blockIdx.z ? Ur : Uu;
  const float* bb = blockIdx.z ? br : bu;
  __shared__ float As1[32][33], As2[32][33], Bs1[32][33], Bs2[32][33];
  const int t = threadIdx.x;
  const int tr = t >> 4, tc = t & 15;
  const int i0 = blockIdx.y * 32, j0 = blockIdx.x * 32;
  const int lr = t >> 3, lc = (t & 7) << 2;
  float a00 = 0.f, a01 = 0.f, a10 = 0.f, a11 = 0.f;
  for (int k0 = 0; k0 < I_DIM; k0 += 32) {
    float4 va1 = *(const float4*)(A1 + (i0 + lr) * I_DIM + k0 + lc);
    float4 va2 = *(const float4*)(A2 + (i0 + lr) * I_DIM + k0 + lc);
    float4 vb1 = *(const float4*)(X + (k0 + lr) * I_DIM + j0 + lc);
    float4 vb2 = *(const float4*)(H + (k0 + lr) * I_DIM + j0 + lc);
    As1[lr][lc] = va1.x; As1[lr][lc + 1] = va1.y; As1[lr][lc + 2] = va1.z; As1[lr][lc + 3] = va1.w;
    As2[lr][lc] = va2.x; As2[lr][lc + 1] = va2.y; As2[lr][lc + 2] = va2.z; As2[lr][lc + 3] = va2.w;
    Bs1[lr][lc] = vb1.x; Bs1[lr][lc + 1] = vb1.y; Bs1[lr][lc + 2] = vb1.z; Bs1[lr][lc + 3] = vb1.w;
    Bs2[lr][lc] = vb2.x; Bs2[lr][lc + 1] = vb2.y; Bs2[lr][lc + 2] = vb2.z; Bs2[lr][lc + 3] = vb2.w;
    __syncthreads();
#pragma unroll
    for (int kk = 0; kk < 32; ++kk) {
      float x0 = As1[tr][kk], x1 = As1[tr + 16][kk];
      float y0 = Bs1[kk][tc], y1 = Bs1[kk][tc + 16];
      a00 = fmaf(x0, y0, a00); a01 = fmaf(x0, y1, a01);
      a10 = fmaf(x1, y0, a10); a11 = fmaf(x1, y1, a11);
      x0 = As2[tr][kk]; x1 = As2[tr + 16][kk];
      y0 = Bs2[kk][tc]; y1 = Bs2[kk][tc + 16];
      a00 = fmaf(x0, y0, a00); a01 = fmaf(x0, y1, a01);
      a10 = fmaf(x1, y0, a10); a11 = fmaf(x1, y1, a11);
    }
    __syncthreads();
  }
  const int ia = i0 + tr, ib = ia + 16;
  const int ja = j0 + tc, jb = ja + 16;
  if (blockIdx.z == 0) {
    int o;
    o = ia * I_DIM + ja; ubuf[o] = sigf(a00 + bb[o]);
    o = ia * I_DIM + jb; ubuf[o] = sigf(a01 + bb[o]);
    o = ib * I_DIM + ja; ubuf[o] = sigf(a10 + bb[o]);
    o = ib * I_DIM + jb; ubuf[o] = sigf(a11 + bb[o]);
  } else {
    int o;
    o = ia * I_DIM + ja; rhbuf[o] = sigf(a00 + bb[o]) * H[o];
    o = ia * I_DIM + jb; rhbuf[o] = sigf(a01 + bb[o]) * H[o];
    o = ib * I_DIM + ja; rhbuf[o] = sigf(a10 + bb[o]) * H[o];
    o = ib * I_DIM + jb; rhbuf[o] = sigf(a11 + bb[o]) * H[o];
  }
}

// ---- kernel 6: hc = tanh(Wh X + Uh RH + bh); out = (1-u)*H + u*hc ----
__global__ __launch_bounds__(256) void k_final(
    const float* __restrict__ Wh, const float* __restrict__ Uh, const float* __restrict__ bh,
    const float* __restrict__ X, const float* __restrict__ RH,
    const float* __restrict__ ubuf, const float* __restrict__ H,
    float* __restrict__ out) {
  __shared__ float As1[32][33], As2[32][33], Bs1[32][33], Bs2[32][33];
  const int t = threadIdx.x;
  const int tr = t >> 4, tc = t & 15;
  const int i0 = blockIdx.y * 32, j0 = blockIdx.x * 32;
  const int lr = t >> 3, lc = (t & 7) << 2;
  float a00 = 0.f, a01 = 0.f, a10 = 0.f, a11 = 0.f;
  for (int k0 = 0; k0 < I_DIM; k0 += 32) {
    float4 va1 = *(const float4*)(Wh + (i0 + lr) * I_DIM + k0 + lc);
    float4 va2 = *(const float4*)(Uh + (i0 + lr) * I_DIM + k0 + lc);
    float4 vb1 = *(const float4*)(X + (k0 + lr) * I_DIM + j0 + lc);
    float4 vb2 = *(const float4*)(RH + (k0 + lr) * I_DIM + j0 + lc);
    As1[lr][lc] = va1.x; As1[lr][lc + 1] = va1.y; As1[lr][lc + 2] = va1.z; As1[lr][lc + 3] = va1.w;
    As2[lr][lc] = va2.x; As2[lr][lc + 1] = va2.y; As2[lr][lc + 2] = va2.z; As2[lr][lc + 3] = va2.w;
    Bs1[lr][lc] = vb1.x; Bs1[lr][lc + 1] = vb1.y; Bs1[lr][lc + 2] = vb1.z; Bs1[lr][lc + 3] = vb1.w;
    Bs2[lr][lc] = vb2.x; Bs2[lr][lc + 1] = vb2.y; Bs2[lr][lc + 2] = vb2.z; Bs2[lr][lc + 3] = vb2.w;
    __syncthreads();
#pragma unroll
    for (int kk = 0; kk < 32; ++kk) {
      float x0 = As1[tr][kk], x1 = As1[tr + 16][kk];
      float y0 = Bs1[kk][tc], y1 = Bs1[kk][tc + 16];
      a00 = fmaf(x0, y0, a00); a01 = fmaf(x0, y1, a01);
      a10 = fmaf(x1, y0, a10); a11 = fmaf(x1, y1, a11);
      x0 = As2[tr][kk]; x1 = As2[tr + 16][kk];
      y0 = Bs2[kk][tc]; y1 = Bs2[kk][tc + 16];
      a00 = fmaf(x0, y0, a00); a01 = fmaf(x0, y1, a01);
      a10 = fmaf(x1, y0, a10); a11 = fmaf(x1, y1, a11);
    }
    __syncthreads();
  }
  const int ia = i0 + tr, ib = ia + 16;
  const int ja = j0 + tc, jb = ja + 16;
  int o;
  float hc, uu;
  o = ia * I_DIM + ja; hc = tanhf(a00 + bh[o]); uu = ubuf[o]; out[o] = (1.f - uu) * H[o] + uu * hc;
  o = ia * I_DIM + jb; hc = tanhf(a01 + bh[o]); uu = ubuf[o]; out[o] = (1.f - uu) * H[o] + uu * hc;
  o = ib * I_DIM + ja; hc = tanhf(a10 + bh[o]); uu = ubuf[o]; out[o] = (1.f - uu) * H[o] + uu * hc;
  o = ib * I_DIM + jb; hc = tanhf(a11 + bh[o]); uu = ubuf[o]; out[o] = (1.f - uu) * H[o] + uu * hc;
}

extern "C" void kernel_launch(void* const* d_in, const int* in_sizes, int n_in,
                              void* d_out, int out_size, void* d_ws, size_t ws_size,
                              hipStream_t stream) {
  const float* inputs = (const float*)d_in[0];
  const float* hist   = (const float*)d_in[1];
  const float* mask   = (const float*)d_in[2];
  const float* scorer = (const float*)d_in[3];
  const float* Wu = (const float*)d_in[4];
  const float* Uu = (const float*)d_in[5];
  const float* bu = (const float*)d_in[6];
  const float* Wr = (const float*)d_in[7];
  const float* Ur = (const float*)d_in[8];
  const float* br = (const float*)d_in[9];
  const float* Wh = (const float*)d_in[10];
  const float* Uh = (const float*)d_in[11];
  const float* bh = (const float*)d_in[12];
  float* out = (float*)d_out;

  char* ws = (char*)d_ws;
  float* inv_norm = (float*)(ws + OFF_NORM);
  unsigned int* ghist = (unsigned int*)(ws + OFF_GHIST);
  unsigned int* keys = (unsigned int*)(ws + OFF_KEYS);
  int* sel_idx = (int*)(ws + OFF_SELIDX);
  float* sel_w = (float*)(ws + OFF_SELW);
  float* X = (float*)(ws + OFF_X);
  float* U = (float*)(ws + OFF_U);
  float* RH = (float*)(ws + OFF_RH);

  k_norm<<<1, 256, 0, stream>>>(scorer, inv_norm, ghist);
  k_scores<<<R_NODES / 4, 256, 0, stream>>>(inputs, scorer, mask, inv_norm, keys);
  k_hist1<<<64, 256, 0, stream>>>(keys, ghist);
  k_select<<<1, 1024, 0, stream>>>(keys, ghist, sel_idx, sel_w);
  k_build_x<<<dim3(16, 16), dim3(32, 8), 0, stream>>>(inputs, sel_idx, sel_w, X);
  k_gates<<<dim3(16, 16, 2), 256, 0, stream>>>(Wu, Uu, bu, Wr, Ur, br, X, hist, U, RH);
  k_final<<<dim3(16, 16), 256, 0, stream>>>(Wh, Uh, bh, X, RH, U, hist, out);
}

// Round 8
// 421.846 us; speedup vs baseline: 1.1922x; 1.1922x over previous
//
#include <hip/hip_runtime.h>

#define R_NODES 100000
#define I_DIM 512
#define K_SEL 512

// ---- workspace layout (bytes) ----
#define OFF_NORM   0                                    // 1 float
#define OFF_GHIST  256                                  // 2048 uint = 8192 B
#define OFF_KEYS   8704                                 // 100000 uint = 400000 B
#define OFF_SELIDX 408832                               // 512 int
#define OFF_SELW   410880                               // 512 float
#define OFF_XT     413696                               // bXt bf16 [j][k] 512*512*2 = 524288
#define OFF_HT     (OFF_XT + 524288)                    // bHt bf16 [j][k] (H^T) 524288
#define OFF_W6     (OFF_HT + 524288)                    // 6 bf16 weights (Wu,Uu,Wr,Ur,Wh,Uh) 6*524288
#define OFF_U      (OFF_W6 + 6 * 524288)                // U f32 [i][j] 1 MB
#define OFF_RHT    (OFF_U + 1048576)                    // bRHt bf16 [j][i] 524288
// total ~6.2 MB

typedef __attribute__((ext_vector_type(8))) short bf16x8;   // MFMA A/B frag (4 VGPR)
typedef __attribute__((ext_vector_type(4))) float f32x4;    // MFMA C/D frag

__device__ __forceinline__ float sigf(float x) { return 1.0f / (1.0f + __expf(-x)); }
__device__ __forceinline__ unsigned short bfr(float x) {   // f32 -> bf16 RNE
  unsigned int u = __float_as_uint(x);
  u += 0x7FFFu + ((u >> 16) & 1u);
  return (unsigned short)(u >> 16);
}
// LDS XOR swizzle for [64 rows][32 k] bf16 tiles (64 B rows): spread 8 rows over 8 16B slots
#define LDS_SWZ(row, bytecol) ((((row) * 64) + (bytecol)) ^ (((row) & 7) << 4))

// ---- kernel 0: scorer norm + zero global histogram (UNCHANGED) ----
__global__ __launch_bounds__(256) void k_norm(const float* __restrict__ scorer,
                                              float* __restrict__ inv_norm,
                                              unsigned int* __restrict__ ghist) {
  __shared__ float red[256];
  int t = threadIdx.x;
  for (int b = t; b < 2048; b += 256) ghist[b] = 0u;
  float v0 = scorer[t], v1 = scorer[t + 256];
  red[t] = v0 * v0 + v1 * v1;
  __syncthreads();
  for (int s = 128; s > 0; s >>= 1) {
    if (t < s) red[t] += red[t + s];
    __syncthreads();
  }
  if (t == 0) inv_norm[0] = 1.0f / (sqrtf(red[0]) + 1e-12f);
}

// ---- kernel 1: scores -> sortable keys (UNCHANGED) ----
__global__ __launch_bounds__(256) void k_scores(const float* __restrict__ inputs,
                                                const float* __restrict__ scorer,
                                                const float* __restrict__ mask,
                                                const float* __restrict__ inv_norm,
                                                unsigned int* __restrict__ keys) {
  const int wave = threadIdx.x >> 6;
  const int lane = threadIdx.x & 63;
  const int row = blockIdx.x * 4 + wave;
  const float4* rp = (const float4*)(inputs + (size_t)row * I_DIM);
  const float4* sp = (const float4*)scorer;
  float4 a0 = rp[lane], a1 = rp[lane + 64];
  float4 s0 = sp[lane], s1 = sp[lane + 64];
  float dot = a0.x * s0.x + a0.y * s0.y + a0.z * s0.z + a0.w * s0.w
            + a1.x * s1.x + a1.y * s1.y + a1.z * s1.z + a1.w * s1.w;
#pragma unroll
  for (int off = 32; off >= 1; off >>= 1) dot += __shfl_down(dot, off);
  if (lane == 0) {
    float score = dot * inv_norm[0] + mask[row];
    unsigned int u = __float_as_uint(score);
    keys[row] = (u & 0x80000000u) ? ~u : (u | 0x80000000u);
  }
}

// ---- kernel 2: grid-wide histogram of top 11 key bits (UNCHANGED) ----
__global__ __launch_bounds__(256) void k_hist1(const unsigned int* __restrict__ keys,
                                               unsigned int* __restrict__ ghist) {
  __shared__ unsigned int h[2048];
  int t = threadIdx.x;
  for (int b = t; b < 2048; b += 256) h[b] = 0u;
  __syncthreads();
  int per = (R_NODES + gridDim.x - 1) / gridDim.x;
  int start = blockIdx.x * per;
  int end = start + per;
  if (end > R_NODES) end = R_NODES;
  for (int r = start + t; r < end; r += 256) atomicAdd(&h[keys[r] >> 21], 1u);
  __syncthreads();
  for (int b = t; b < 2048; b += 256) {
    unsigned int v = h[b];
    if (v) atomicAdd(&ghist[b], v);
  }
}

// ---- kernel 3: radix refine + compact + bitonic sort (UNCHANGED) ----
#define SUFFIX_SCAN()                                                         \
  for (int off = 1; off < 2048; off <<= 1) {                                  \
    unsigned int v0 = (t + off < 2048) ? hist[t + off] : 0u;                  \
    unsigned int v1 = (t + 1024 + off < 2048) ? hist[t + 1024 + off] : 0u;    \
    __syncthreads();                                                          \
    hist[t] += v0;                                                            \
    hist[t + 1024] += v1;                                                     \
    __syncthreads();                                                          \
  }

#define FIND_BIN(needv)                                                       \
  {                                                                           \
    for (int q = 0; q < 2; ++q) {                                             \
      int b = t + q * 1024;                                                   \
      unsigned int s_here = hist[b];                                          \
      unsigned int s_next = (b < 2047) ? hist[b + 1] : 0u;                    \
      if (s_here >= (needv) && s_next < (needv)) {                            \
        sh_bin = (unsigned int)b;                                             \
        sh_above = s_next;                                                    \
      }                                                                       \
    }                                                                         \
    __syncthreads();                                                          \
  }

__global__ __launch_bounds__(1024) void k_select(const unsigned int* __restrict__ keys,
                                                 const unsigned int* __restrict__ ghist,
                                                 int* __restrict__ sel_idx,
                                                 float* __restrict__ sel_w) {
  __shared__ unsigned int hist[2048];
  __shared__ unsigned long long cand[2048];
  __shared__ unsigned int sh_bin, sh_above, sh_cnt;
  const int t = threadIdx.x;

  unsigned int need = K_SEL;
  hist[t] = ghist[t];
  hist[t + 1024] = ghist[t + 1024];
  __syncthreads();
  SUFFIX_SCAN();
  FIND_BIN(need);
  unsigned int b1 = sh_bin;
  need -= sh_above;
  __syncthreads();

  hist[t] = 0u;
  hist[t + 1024] = 0u;
  __syncthreads();
  for (int r = t; r < R_NODES; r += 1024) {
    unsigned int k2 = keys[r];
    if ((k2 >> 21) == b1) atomicAdd(&hist[(k2 >> 10) & 0x7FFu], 1u);
  }
  __syncthreads();
  SUFFIX_SCAN();
  FIND_BIN(need);
  unsigned int b2 = sh_bin;
  unsigned int T = ((b1 << 11) | b2) << 10;

  if (t == 0) sh_cnt = 0u;
  __syncthreads();
  for (int r = t; r < R_NODES; r += 1024) {
    unsigned int k2 = keys[r];
    if (k2 >= T) {
      unsigned int p = atomicAdd(&sh_cnt, 1u);
      if (p < 2048u)
        cand[p] = ((unsigned long long)k2 << 32) |
                  (unsigned long long)(0xFFFFFFFFu - (unsigned int)r);
    }
  }
  __syncthreads();
  unsigned int cnt = sh_cnt > 2048u ? 2048u : sh_cnt;
  for (int p = t; p < 2048; p += 1024)
    if ((unsigned int)p >= cnt) cand[p] = 0ULL;
  __syncthreads();

  for (int ks = 2; ks <= 2048; ks <<= 1) {
    for (int js = ks >> 1; js > 0; js >>= 1) {
      for (int i = t; i < 2048; i += 1024) {
        int ixj = i ^ js;
        if (ixj > i) {
          unsigned long long x = cand[i], y = cand[ixj];
          bool up = ((i & ks) == 0);
          if (up ? (x > y) : (x < y)) {
            cand[i] = y;
            cand[ixj] = x;
          }
        }
      }
      __syncthreads();
    }
  }

  for (int j = t; j < K_SEL; j += 1024) {
    unsigned long long c = cand[2047 - j];
    unsigned int key = (unsigned int)(c >> 32);
    unsigned int ridx = 0xFFFFFFFFu - (unsigned int)(c & 0xFFFFFFFFull);
    unsigned int ub = (key & 0x80000000u) ? (key ^ 0x80000000u) : ~key;
    float val = __uint_as_float(ub);
    sel_idx[j] = (int)ridx;
    sel_w[j] = tanhf(val);
  }
}

// ---- kernel 4: convert weights to bf16; build H^T bf16 ----
// grid (256, 7): y<6 -> straight cvt of weight y; y==6 -> 32x32 tiled transpose of hist
__global__ __launch_bounds__(256) void k_cvt(
    const float* __restrict__ Wu, const float* __restrict__ Uu,
    const float* __restrict__ Wr, const float* __restrict__ Ur,
    const float* __restrict__ Wh, const float* __restrict__ Uh,
    const float* __restrict__ hist,
    unsigned short* __restrict__ bW,      // 6 matrices back-to-back
    unsigned short* __restrict__ bHt) {
  const int t = threadIdx.x;
  const int y = blockIdx.y;
  if (y < 6) {
    const float* srcs[6] = {Wu, Uu, Wr, Ur, Wh, Uh};
    const float* src = srcs[y];
    unsigned short* dst = bW + (size_t)y * (I_DIM * I_DIM);
    int idx4 = blockIdx.x * 256 + t;  // 256 blocks * 256 thr * 4 = 262144
    float4 v = ((const float4*)src)[idx4];
    ushort4 o;
    o.x = bfr(v.x); o.y = bfr(v.y); o.z = bfr(v.z); o.w = bfr(v.w);
    ((ushort4*)dst)[idx4] = o;
  } else {
    __shared__ float tile[32][33];
    const int ti = blockIdx.x >> 4;   // source row tile
    const int tj = blockIdx.x & 15;   // source col tile
    const int r = t >> 3;
    const int cq = (t & 7) * 4;
    float4 v = *(const float4*)&hist[(ti * 32 + r) * I_DIM + tj * 32 + cq];
    tile[r][cq + 0] = v.x; tile[r][cq + 1] = v.y;
    tile[r][cq + 2] = v.z; tile[r][cq + 3] = v.w;
    __syncthreads();
    ushort4 o;
    o.x = bfr(tile[cq + 0][r]);
    o.y = bfr(tile[cq + 1][r]);
    o.z = bfr(tile[cq + 2][r]);
    o.w = bfr(tile[cq + 3][r]);
    *(ushort4*)&bHt[(tj * 32 + r) * I_DIM + ti * 32 + cq] = o;
  }
}

// ---- kernel 5: bXt[j][k] = inputs[idx_j][k] * w_j  (bf16, direct coalesced) ----
__global__ __launch_bounds__(256) void k_build_xt(const float* __restrict__ inputs,
                                                  const int* __restrict__ sel_idx,
                                                  const float* __restrict__ sel_w,
                                                  unsigned short* __restrict__ bXt) {
  const int j = blockIdx.x;
  const int c = threadIdx.x;
  const int row = sel_idx[j];
  const float w = sel_w[j];
  float2 v = *(const float2*)&inputs[(size_t)row * I_DIM + c * 2];
  ushort2 o;
  o.x = bfr(v.x * w);
  o.y = bfr(v.y * w);
  *(ushort2*)&bXt[(size_t)j * I_DIM + c * 2] = o;
}

// ---- MFMA GEMM core: D(64x64 at i0,j0) = A1(512-K)@B1 + A2@B2, bf16 in, f32 acc ----
// A tiles: rows of A1/A2 (i0..i0+63, k-contig).  B tiles: rows of B1t/B2t ([col][k], k-contig).
// 4 waves 2x2; each wave 32x32 = 2x2 16x16 frags; K-step 32.
__device__ __forceinline__ void gemm64_dual(
    const unsigned short* __restrict__ A1, const unsigned short* __restrict__ A2,
    const unsigned short* __restrict__ B1t, const unsigned short* __restrict__ B2t,
    int i0, int j0, char* smem, f32x4 acc[2][2]) {
  const int t = threadIdx.x;
  const int w = t >> 6, l = t & 63;
  const int wm = w >> 1, wn = w & 1;
  const int lr = l & 15, lh = l >> 4;
  char* sA1 = smem;
  char* sA2 = smem + 4096;
  char* sB1 = smem + 8192;
  char* sB2 = smem + 12288;
  const int srow = t >> 2;          // staging: row 0..63
  const int kc = t & 3;             // 8-bf16 chunk 0..3
  const int sbyte = LDS_SWZ(srow, kc * 16);

  for (int ks = 0; ks < I_DIM / 32; ++ks) {
    const size_t ga = (size_t)(i0 + srow) * I_DIM + ks * 32 + kc * 8;
    const size_t gb = (size_t)(j0 + srow) * I_DIM + ks * 32 + kc * 8;
    uint4 va1 = *(const uint4*)(A1 + ga);
    uint4 va2 = *(const uint4*)(A2 + ga);
    uint4 vb1 = *(const uint4*)(B1t + gb);
    uint4 vb2 = *(const uint4*)(B2t + gb);
    __syncthreads();                 // protect prior iteration's reads
    *(uint4*)(sA1 + sbyte) = va1;
    *(uint4*)(sA2 + sbyte) = va2;
    *(uint4*)(sB1 + sbyte) = vb1;
    *(uint4*)(sB2 + sbyte) = vb2;
    __syncthreads();
    bf16x8 a1[2], a2[2], b1[2], b2[2];
#pragma unroll
    for (int mf = 0; mf < 2; ++mf) {
      int rowA = wm * 32 + mf * 16 + lr;
      int off = LDS_SWZ(rowA, lh * 16);
      a1[mf] = *(const bf16x8*)(sA1 + off);
      a2[mf] = *(const bf16x8*)(sA2 + off);
    }
#pragma unroll
    for (int nf = 0; nf < 2; ++nf) {
      int rowB = wn * 32 + nf * 16 + lr;
      int off = LDS_SWZ(rowB, lh * 16);
      b1[nf] = *(const bf16x8*)(sB1 + off);
      b2[nf] = *(const bf16x8*)(sB2 + off);
    }
#pragma unroll
    for (int mf = 0; mf < 2; ++mf)
#pragma unroll
      for (int nf = 0; nf < 2; ++nf) {
        acc[mf][nf] = __builtin_amdgcn_mfma_f32_16x16x32_bf16(a1[mf], b1[nf], acc[mf][nf], 0, 0, 0);
        acc[mf][nf] = __builtin_amdgcn_mfma_f32_16x16x32_bf16(a2[mf], b2[nf], acc[mf][nf], 0, 0, 0);
      }
  }
}

// ---- kernel 6: gates. z=0: U=sigmoid(Wu X + Uu H + bu); z=1: RHt=sigmoid(Wr X + Ur H + br)*H ----
__global__ __launch_bounds__(256) void k_gates_mfma(
    const unsigned short* __restrict__ bW, const unsigned short* __restrict__ bXt,
    const unsigned short* __restrict__ bHt,
    const float* __restrict__ bu, const float* __restrict__ br,
    const float* __restrict__ hist,
    float* __restrict__ U, unsigned short* __restrict__ bRHt) {
  __shared__ char smem[16384];
  const int i0 = blockIdx.y * 64, j0 = blockIdx.x * 64;
  const int z = blockIdx.z;
  const unsigned short* A1 = bW + (size_t)(z ? 2 : 0) * (I_DIM * I_DIM);  // Wu or Wr
  const unsigned short* A2 = bW + (size_t)(z ? 3 : 1) * (I_DIM * I_DIM);  // Uu or Ur
  f32x4 acc[2][2];
#pragma unroll
  for (int mf = 0; mf < 2; ++mf)
#pragma unroll
    for (int nf = 0; nf < 2; ++nf) acc[mf][nf] = (f32x4){0.f, 0.f, 0.f, 0.f};
  gemm64_dual(A1, A2, bXt, bHt, i0, j0, smem, acc);

  const int t = threadIdx.x;
  const int w = t >> 6, l = t & 63;
  const int wm = w >> 1, wn = w & 1;
  const int lr = l & 15, lh = l >> 4;
  const float* bias = z ? br : bu;
#pragma unroll
  for (int mf = 0; mf < 2; ++mf)
#pragma unroll
    for (int nf = 0; nf < 2; ++nf)
#pragma unroll
      for (int q = 0; q < 4; ++q) {
        int row = i0 + wm * 32 + mf * 16 + lh * 4 + q;
        int col = j0 + wn * 32 + nf * 16 + lr;
        int o = row * I_DIM + col;
        float g = sigf(acc[mf][nf][q] + bias[o]);
        if (z == 0) {
          U[o] = g;
        } else {
          bRHt[(size_t)col * I_DIM + row] = bfr(g * hist[o]);
        }
      }
}

// ---- kernel 7: hc = tanh(Wh X + Uh RH + bh); out = (1-u)*H + u*hc ----
__global__ __launch_bounds__(256) void k_final_mfma(
    const unsigned short* __restrict__ bW, const unsigned short* __restrict__ bXt,
    const unsigned short* __restrict__ bRHt,
    const float* __restrict__ bh, const float* __restrict__ U,
    const float* __restrict__ hist, float* __restrict__ out) {
  __shared__ char smem[16384];
  const int i0 = blockIdx.y * 64, j0 = blockIdx.x * 64;
  const unsigned short* A1 = bW + (size_t)4 * (I_DIM * I_DIM);  // Wh
  const unsigned short* A2 = bW + (size_t)5 * (I_DIM * I_DIM);  // Uh
  f32x4 acc[2][2];
#pragma unroll
  for (int mf = 0; mf < 2; ++mf)
#pragma unroll
    for (int nf = 0; nf < 2; ++nf) acc[mf][nf] = (f32x4){0.f, 0.f, 0.f, 0.f};
  gemm64_dual(A1, A2, bXt, bRHt, i0, j0, smem, acc);

  const int t = threadIdx.x;
  const int w = t >> 6, l = t & 63;
  const int wm = w >> 1, wn = w & 1;
  const int lr = l & 15, lh = l >> 4;
#pragma unroll
  for (int mf = 0; mf < 2; ++mf)
#pragma unroll
    for (int nf = 0; nf < 2; ++nf)
#pragma unroll
      for (int q = 0; q < 4; ++q) {
        int row = i0 + wm * 32 + mf * 16 + lh * 4 + q;
        int col = j0 + wn * 32 + nf * 16 + lr;
        int o = row * I_DIM + col;
        float hc = tanhf(acc[mf][nf][q] + bh[o]);
        float uu = U[o];
        out[o] = (1.f - uu) * hist[o] + uu * hc;
      }
}

extern "C" void kernel_launch(void* const* d_in, const int* in_sizes, int n_in,
                              void* d_out, int out_size, void* d_ws, size_t ws_size,
                              hipStream_t stream) {
  const float* inputs = (const float*)d_in[0];
  const float* hist   = (const float*)d_in[1];
  const float* mask   = (const float*)d_in[2];
  const float* scorer = (const float*)d_in[3];
  const float* Wu = (const float*)d_in[4];
  const float* Uu = (const float*)d_in[5];
  const float* bu = (const float*)d_in[6];
  const float* Wr = (const float*)d_in[7];
  const float* Ur = (const float*)d_in[8];
  const float* br = (const float*)d_in[9];
  const float* Wh = (const float*)d_in[10];
  const float* Uh = (const float*)d_in[11];
  const float* bh = (const float*)d_in[12];
  float* out = (float*)d_out;

  char* ws = (char*)d_ws;
  float* inv_norm = (float*)(ws + OFF_NORM);
  unsigned int* ghist = (unsigned int*)(ws + OFF_GHIST);
  unsigned int* keys = (unsigned int*)(ws + OFF_KEYS);
  int* sel_idx = (int*)(ws + OFF_SELIDX);
  float* sel_w = (float*)(ws + OFF_SELW);
  unsigned short* bXt = (unsigned short*)(ws + OFF_XT);
  unsigned short* bHt = (unsigned short*)(ws + OFF_HT);
  unsigned short* bW  = (unsigned short*)(ws + OFF_W6);
  float* U = (float*)(ws + OFF_U);
  unsigned short* bRHt = (unsigned short*)(ws + OFF_RHT);

  k_cvt<<<dim3(256, 7), 256, 0, stream>>>(Wu, Uu, Wr, Ur, Wh, Uh, hist, bW, bHt);
  k_norm<<<1, 256, 0, stream>>>(scorer, inv_norm, ghist);
  k_scores<<<R_NODES / 4, 256, 0, stream>>>(inputs, scorer, mask, inv_norm, keys);
  k_hist1<<<64, 256, 0, stream>>>(keys, ghist);
  k_select<<<1, 1024, 0, stream>>>(keys, ghist, sel_idx, sel_w);
  k_build_xt<<<512, 256, 0, stream>>>(inputs, sel_idx, sel_w, bXt);
  k_gates_mfma<<<dim3(8, 8, 2), 256, 0, stream>>>(bW, bXt, bHt, bu, br, hist, U, bRHt);
  k_final_mfma<<<dim3(8, 8), 256, 0, stream>>>(bW, bXt, bRHt, bh, U, hist, out);
}

// Round 11
// 389.528 us; speedup vs baseline: 1.2911x; 1.0830x over previous
//
#include <hip/hip_runtime.h>

#define R_NODES 100000
#define I_DIM 512
#define K_SEL 512

// ---- workspace layout (bytes) ----
#define OFF_NORM   0                                    // 1 float
#define OFF_GHIST  256                                  // 2048 uint = 8192 B
#define OFF_KEYS   8704                                 // 100000 uint = 400000 B
#define OFF_SELIDX 408832                               // 512 int
#define OFF_SELW   410880                               // 512 float
#define OFF_XT     413696                               // bXt bf16 [j][k] 512*512*2 = 524288
#define OFF_HT     (OFF_XT + 524288)                    // bHt bf16 [j][k] (H^T) 524288
#define OFF_W6     (OFF_HT + 524288)                    // 6 bf16 weights (Wu,Uu,Wr,Ur,Wh,Uh)
#define OFF_U      (OFF_W6 + 6 * 524288)                // U f32 [i][j] 1 MB
#define OFF_RHT    (OFF_U + 1048576)                    // bRHt bf16 [j][i] 524288
// total ~6.2 MB

typedef __attribute__((ext_vector_type(8))) short bf16x8;   // MFMA A/B frag (4 VGPR)
typedef __attribute__((ext_vector_type(4))) float f32x4;    // MFMA C/D frag

__device__ __forceinline__ float sigf(float x) { return 1.0f / (1.0f + __expf(-x)); }
__device__ __forceinline__ unsigned short bfr(float x) {   // f32 -> bf16 RNE
  unsigned int u = __float_as_uint(x);
  u += 0x7FFFu + ((u >> 16) & 1u);
  return (unsigned short)(u >> 16);
}
// LDS XOR swizzle for [64 rows][32 k] bf16 tiles (64 B rows)
#define LDS_SWZ(row, bytecol) ((((row) * 64) + (bytecol)) ^ (((row) & 7) << 4))

// ---- kernel 1: scores -> sortable keys (UNCHANGED) ----
__global__ __launch_bounds__(256) void k_scores(const float* __restrict__ inputs,
                                                const float* __restrict__ scorer,
                                                const float* __restrict__ mask,
                                                const float* __restrict__ inv_norm,
                                                unsigned int* __restrict__ keys) {
  const int wave = threadIdx.x >> 6;
  const int lane = threadIdx.x & 63;
  const int row = blockIdx.x * 4 + wave;
  const float4* rp = (const float4*)(inputs + (size_t)row * I_DIM);
  const float4* sp = (const float4*)scorer;
  float4 a0 = rp[lane], a1 = rp[lane + 64];
  float4 s0 = sp[lane], s1 = sp[lane + 64];
  float dot = a0.x * s0.x + a0.y * s0.y + a0.z * s0.z + a0.w * s0.w
            + a1.x * s1.x + a1.y * s1.y + a1.z * s1.z + a1.w * s1.w;
#pragma unroll
  for (int off = 32; off >= 1; off >>= 1) dot += __shfl_down(dot, off);
  if (lane == 0) {
    float score = dot * inv_norm[0] + mask[row];
    unsigned int u = __float_as_uint(score);
    keys[row] = (u & 0x80000000u) ? ~u : (u | 0x80000000u);
  }
}

// ---- kernel 2: grid-wide histogram of top 11 key bits (UNCHANGED) ----
__global__ __launch_bounds__(256) void k_hist1(const unsigned int* __restrict__ keys,
                                               unsigned int* __restrict__ ghist) {
  __shared__ unsigned int h[2048];
  int t = threadIdx.x;
  for (int b = t; b < 2048; b += 256) h[b] = 0u;
  __syncthreads();
  int per = (R_NODES + gridDim.x - 1) / gridDim.x;
  int start = blockIdx.x * per;
  int end = start + per;
  if (end > R_NODES) end = R_NODES;
  for (int r = start + t; r < end; r += 256) atomicAdd(&h[keys[r] >> 21], 1u);
  __syncthreads();
  for (int b = t; b < 2048; b += 256) {
    unsigned int v = h[b];
    if (v) atomicAdd(&ghist[b], v);
  }
}

// ---- kernel 3 (v2): find crossing bin b1 -> ONE sweep capturing all keys with
// bin >= b1 (every such key dominates every key below; suffix(b1) >= 512) ->
// adaptive bitonic (1024 when cnt fits, 2048 fallback) -> sel_idx, sel_w ----
#define SUFFIX_SCAN()                                                         \
  for (int off = 1; off < 2048; off <<= 1) {                                  \
    unsigned int v0 = (t + off < 2048) ? hist[t + off] : 0u;                  \
    unsigned int v1 = (t + 1024 + off < 2048) ? hist[t + 1024 + off] : 0u;    \
    __syncthreads();                                                          \
    hist[t] += v0;                                                            \
    hist[t + 1024] += v1;                                                     \
    __syncthreads();                                                          \
  }

#define FIND_BIN(needv)                                                       \
  {                                                                           \
    for (int q = 0; q < 2; ++q) {                                             \
      int b = t + q * 1024;                                                   \
      unsigned int s_here = hist[b];                                          \
      unsigned int s_next = (b < 2047) ? hist[b + 1] : 0u;                    \
      if (s_here >= (needv) && s_next < (needv)) {                            \
        sh_bin = (unsigned int)b;                                             \
      }                                                                       \
    }                                                                         \
    __syncthreads();                                                          \
  }

__global__ __launch_bounds__(1024) void k_select(const unsigned int* __restrict__ keys,
                                                 const unsigned int* __restrict__ ghist,
                                                 int* __restrict__ sel_idx,
                                                 float* __restrict__ sel_w) {
  __shared__ unsigned int hist[2048];
  __shared__ unsigned long long cand[2048];
  __shared__ unsigned int sh_bin, sh_cnt;
  const int t = threadIdx.x;

  hist[t] = ghist[t];
  hist[t + 1024] = ghist[t + 1024];
  __syncthreads();
  SUFFIX_SCAN();
  FIND_BIN(K_SEL);
  unsigned int b1 = sh_bin;
  if (t == 0) sh_cnt = 0u;
  __syncthreads();

  // single sweep: capture every key with top-11 bits >= b1
  const unsigned int kmin = b1 << 21;
  for (int r = t; r < R_NODES; r += 1024) {
    unsigned int k2 = keys[r];
    if (k2 >= kmin) {
      unsigned int p = atomicAdd(&sh_cnt, 1u);
      if (p < 2048u)
        cand[p] = ((unsigned long long)k2 << 32) |
                  (unsigned long long)(0xFFFFFFFFu - (unsigned int)r);
    }
  }
  __syncthreads();
  const unsigned int cnt = sh_cnt > 2048u ? 2048u : sh_cnt;
  const int nsort = (cnt <= 1024u) ? 1024 : 2048;
  for (int p = t; p < nsort; p += 1024)
    if ((unsigned int)p >= cnt) cand[p] = 0ULL;
  __syncthreads();

  // bitonic ascending sort of nsort composites (key, ~idx)
  for (int ks = 2; ks <= nsort; ks <<= 1) {
    for (int js = ks >> 1; js > 0; js >>= 1) {
      for (int i = t; i < nsort; i += 1024) {
        int ixj = i ^ js;
        if (ixj > i) {
          unsigned long long x = cand[i], y = cand[ixj];
          bool up = ((i & ks) == 0);
          if (up ? (x > y) : (x < y)) {
            cand[i] = y;
            cand[ixj] = x;
          }
        }
      }
      __syncthreads();
    }
  }

  // top 512 = largest composites from the tail (desc key, asc idx on ties)
  for (int j = t; j < K_SEL; j += 1024) {
    unsigned long long c = cand[nsort - 1 - j];
    unsigned int key = (unsigned int)(c >> 32);
    unsigned int ridx = 0xFFFFFFFFu - (unsigned int)(c & 0xFFFFFFFFull);
    unsigned int ub = (key & 0x80000000u) ? (key ^ 0x80000000u) : ~key;
    float val = __uint_as_float(ub);
    sel_idx[j] = (int)ridx;
    sel_w[j] = tanhf(val);
  }
}

// ---- kernel 4: weights->bf16, H^T->bf16, and (y==7) scorer norm + ghist zero ----
__global__ __launch_bounds__(256) void k_cvt(
    const float* __restrict__ Wu, const float* __restrict__ Uu,
    const float* __restrict__ Wr, const float* __restrict__ Ur,
    const float* __restrict__ Wh, const float* __restrict__ Uh,
    const float* __restrict__ hist,
    const float* __restrict__ scorer,
    unsigned short* __restrict__ bW,      // 6 matrices back-to-back
    unsigned short* __restrict__ bHt,
    float* __restrict__ inv_norm,
    unsigned int* __restrict__ ghist) {
  const int t = threadIdx.x;
  const int y = blockIdx.y;
  if (y < 6) {
    const float* srcs[6] = {Wu, Uu, Wr, Ur, Wh, Uh};
    const float* src = srcs[y];
    unsigned short* dst = bW + (size_t)y * (I_DIM * I_DIM);
    int idx4 = blockIdx.x * 256 + t;  // 256 blocks * 256 thr * 4 = 262144
    float4 v = ((const float4*)src)[idx4];
    ushort4 o;
    o.x = bfr(v.x); o.y = bfr(v.y); o.z = bfr(v.z); o.w = bfr(v.w);
    ((ushort4*)dst)[idx4] = o;
  } else if (y == 6) {
    __shared__ float tile[32][33];
    const int ti = blockIdx.x >> 4;   // source row tile
    const int tj = blockIdx.x & 15;   // source col tile
    const int r = t >> 3;
    const int cq = (t & 7) * 4;
    float4 v = *(const float4*)&hist[(ti * 32 + r) * I_DIM + tj * 32 + cq];
    tile[r][cq + 0] = v.x; tile[r][cq + 1] = v.y;
    tile[r][cq + 2] = v.z; tile[r][cq + 3] = v.w;
    __syncthreads();
    ushort4 o;
    o.x = bfr(tile[cq + 0][r]);
    o.y = bfr(tile[cq + 1][r]);
    o.z = bfr(tile[cq + 2][r]);
    o.w = bfr(tile[cq + 3][r]);
    *(ushort4*)&bHt[(tj * 32 + r) * I_DIM + ti * 32 + cq] = o;
  } else {
    if (blockIdx.x != 0) return;
    __shared__ float red[256];
    for (int b = t; b < 2048; b += 256) ghist[b] = 0u;
    float v0 = scorer[t], v1 = scorer[t + 256];
    red[t] = v0 * v0 + v1 * v1;
    __syncthreads();
    for (int s = 128; s > 0; s >>= 1) {
      if (t < s) red[t] += red[t + s];
      __syncthreads();
    }
    if (t == 0) inv_norm[0] = 1.0f / (sqrtf(red[0]) + 1e-12f);
  }
}

// ---- kernel 5: bXt[j][k] = inputs[idx_j][k] * w_j  (bf16, direct coalesced) ----
__global__ __launch_bounds__(256) void k_build_xt(const float* __restrict__ inputs,
                                                  const int* __restrict__ sel_idx,
                                                  const float* __restrict__ sel_w,
                                                  unsigned short* __restrict__ bXt) {
  const int j = blockIdx.x;
  const int c = threadIdx.x;
  const int row = sel_idx[j];
  const float w = sel_w[j];
  float2 v = *(const float2*)&inputs[(size_t)row * I_DIM + c * 2];
  ushort2 o;
  o.x = bfr(v.x * w);
  o.y = bfr(v.y * w);
  *(ushort2*)&bXt[(size_t)j * I_DIM + c * 2] = o;
}

// ---- MFMA GEMM core (UNCHANGED): D(64x64) = A1@B1 + A2@B2, bf16 in, f32 acc ----
__device__ __forceinline__ void gemm64_dual(
    const unsigned short* __restrict__ A1, const unsigned short* __restrict__ A2,
    const unsigned short* __restrict__ B1t, const unsigned short* __restrict__ B2t,
    int i0, int j0, char* smem, f32x4 acc[2][2]) {
  const int t = threadIdx.x;
  const int w = t >> 6, l = t & 63;
  const int wm = w >> 1, wn = w & 1;
  const int lr = l & 15, lh = l >> 4;
  char* sA1 = smem;
  char* sA2 = smem + 4096;
  char* sB1 = smem + 8192;
  char* sB2 = smem + 12288;
  const int srow = t >> 2;
  const int kc = t & 3;
  const int sbyte = LDS_SWZ(srow, kc * 16);

  for (int ks = 0; ks < I_DIM / 32; ++ks) {
    const size_t ga = (size_t)(i0 + srow) * I_DIM + ks * 32 + kc * 8;
    const size_t gb = (size_t)(j0 + srow) * I_DIM + ks * 32 + kc * 8;
    uint4 va1 = *(const uint4*)(A1 + ga);
    uint4 va2 = *(const uint4*)(A2 + ga);
    uint4 vb1 = *(const uint4*)(B1t + gb);
    uint4 vb2 = *(const uint4*)(B2t + gb);
    __syncthreads();
    *(uint4*)(sA1 + sbyte) = va1;
    *(uint4*)(sA2 + sbyte) = va2;
    *(uint4*)(sB1 + sbyte) = vb1;
    *(uint4*)(sB2 + sbyte) = vb2;
    __syncthreads();
    bf16x8 a1[2], a2[2], b1[2], b2[2];
#pragma unroll
    for (int mf = 0; mf < 2; ++mf) {
      int rowA = wm * 32 + mf * 16 + lr;
      int off = LDS_SWZ(rowA, lh * 16);
      a1[mf] = *(const bf16x8*)(sA1 + off);
      a2[mf] = *(const bf16x8*)(sA2 + off);
    }
#pragma unroll
    for (int nf = 0; nf < 2; ++nf) {
      int rowB = wn * 32 + nf * 16 + lr;
      int off = LDS_SWZ(rowB, lh * 16);
      b1[nf] = *(const bf16x8*)(sB1 + off);
      b2[nf] = *(const bf16x8*)(sB2 + off);
    }
#pragma unroll
    for (int mf = 0; mf < 2; ++mf)
#pragma unroll
      for (int nf = 0; nf < 2; ++nf) {
        acc[mf][nf] = __builtin_amdgcn_mfma_f32_16x16x32_bf16(a1[mf], b1[nf], acc[mf][nf], 0, 0, 0);
        acc[mf][nf] = __builtin_amdgcn_mfma_f32_16x16x32_bf16(a2[mf], b2[nf], acc[mf][nf], 0, 0, 0);
      }
  }
}

// ---- kernel 6: gates (UNCHANGED) ----
__global__ __launch_bounds__(256) void k_gates_mfma(
    const unsigned short* __restrict__ bW, const unsigned short* __restrict__ bXt,
    const unsigned short* __restrict__ bHt,
    const float* __restrict__ bu, const float* __restrict__ br,
    const float* __restrict__ hist,
    float* __restrict__ U, unsigned short* __restrict__ bRHt) {
  __shared__ char smem[16384];
  const int i0 = blockIdx.y * 64, j0 = blockIdx.x * 64;
  const int z = blockIdx.z;
  const unsigned short* A1 = bW + (size_t)(z ? 2 : 0) * (I_DIM * I_DIM);
  const unsigned short* A2 = bW + (size_t)(z ? 3 : 1) * (I_DIM * I_DIM);
  f32x4 acc[2][2];
#pragma unroll
  for (int mf = 0; mf < 2; ++mf)
#pragma unroll
    for (int nf = 0; nf < 2; ++nf) acc[mf][nf] = (f32x4){0.f, 0.f, 0.f, 0.f};
  gemm64_dual(A1, A2, bXt, bHt, i0, j0, smem, acc);

  const int t = threadIdx.x;
  const int w = t >> 6, l = t & 63;
  const int wm = w >> 1, wn = w & 1;
  const int lr = l & 15, lh = l >> 4;
  const float* bias = z ? br : bu;
#pragma unroll
  for (int mf = 0; mf < 2; ++mf)
#pragma unroll
    for (int nf = 0; nf < 2; ++nf)
#pragma unroll
      for (int q = 0; q < 4; ++q) {
        int row = i0 + wm * 32 + mf * 16 + lh * 4 + q;
        int col = j0 + wn * 32 + nf * 16 + lr;
        int o = row * I_DIM + col;
        float g = sigf(acc[mf][nf][q] + bias[o]);
        if (z == 0) {
          U[o] = g;
        } else {
          bRHt[(size_t)col * I_DIM + row] = bfr(g * hist[o]);
        }
      }
}

// ---- kernel 7: final (UNCHANGED) ----
__global__ __launch_bounds__(256) void k_final_mfma(
    const unsigned short* __restrict__ bW, const unsigned short* __restrict__ bXt,
    const unsigned short* __restrict__ bRHt,
    const float* __restrict__ bh, const float* __restrict__ U,
    const float* __restrict__ hist, float* __restrict__ out) {
  __shared__ char smem[16384];
  const int i0 = blockIdx.y * 64, j0 = blockIdx.x * 64;
  const unsigned short* A1 = bW + (size_t)4 * (I_DIM * I_DIM);
  const unsigned short* A2 = bW + (size_t)5 * (I_DIM * I_DIM);
  f32x4 acc[2][2];
#pragma unroll
  for (int mf = 0; mf < 2; ++mf)
#pragma unroll
    for (int nf = 0; nf < 2; ++nf) acc[mf][nf] = (f32x4){0.f, 0.f, 0.f, 0.f};
  gemm64_dual(A1, A2, bXt, bRHt, i0, j0, smem, acc);

  const int t = threadIdx.x;
  const int w = t >> 6, l = t & 63;
  const int wm = w >> 1, wn = w & 1;
  const int lr = l & 15, lh = l >> 4;
#pragma unroll
  for (int mf = 0; mf < 2; ++mf)
#pragma unroll
    for (int nf = 0; nf < 2; ++nf)
#pragma unroll
      for (int q = 0; q < 4; ++q) {
        int row = i0 + wm * 32 + mf * 16 + lh * 4 + q;
        int col = j0 + wn * 32 + nf * 16 + lr;
        int o = row * I_DIM + col;
        float hc = tanhf(acc[mf][nf][q] + bh[o]);
        float uu = U[o];
        out[o] = (1.f - uu) * hist[o] + uu * hc;
      }
}

extern "C" void kernel_launch(void* const* d_in, const int* in_sizes, int n_in,
                              void* d_out, int out_size, void* d_ws, size_t ws_size,
                              hipStream_t stream) {
  const float* inputs = (const float*)d_in[0];
  const float* hist   = (const float*)d_in[1];
  const float* mask   = (const float*)d_in[2];
  const float* scorer = (const float*)d_in[3];
  const float* Wu = (const float*)d_in[4];
  const float* Uu = (const float*)d_in[5];
  const float* bu = (const float*)d_in[6];
  const float* Wr = (const float*)d_in[7];
  const float* Ur = (const float*)d_in[8];
  const float* br = (const float*)d_in[9];
  const float* Wh = (const float*)d_in[10];
  const float* Uh = (const float*)d_in[11];
  const float* bh = (const float*)d_in[12];
  float* out = (float*)d_out;

  char* ws = (char*)d_ws;
  float* inv_norm = (float*)(ws + OFF_NORM);
  unsigned int* ghist = (unsigned int*)(ws + OFF_GHIST);
  unsigned int* keys = (unsigned int*)(ws + OFF_KEYS);
  int* sel_idx = (int*)(ws + OFF_SELIDX);
  float* sel_w = (float*)(ws + OFF_SELW);
  unsigned short* bXt = (unsigned short*)(ws + OFF_XT);
  unsigned short* bHt = (unsigned short*)(ws + OFF_HT);
  unsigned short* bW  = (unsigned short*)(ws + OFF_W6);
  float* U = (float*)(ws + OFF_U);
  unsigned short* bRHt = (unsigned short*)(ws + OFF_RHT);

  k_cvt<<<dim3(256, 8), 256, 0, stream>>>(Wu, Uu, Wr, Ur, Wh, Uh, hist, scorer,
                                          bW, bHt, inv_norm, ghist);
  k_scores<<<R_NODES / 4, 256, 0, stream>>>(inputs, scorer, mask, inv_norm, keys);
  k_hist1<<<64, 256, 0, stream>>>(keys, ghist);
  k_select<<<1, 1024, 0, stream>>>(keys, ghist, sel_idx, sel_w);
  k_build_xt<<<512, 256, 0, stream>>>(inputs, sel_idx, sel_w, bXt);
  k_gates_mfma<<<dim3(8, 8, 2), 256, 0, stream>>>(bW, bXt, bHt, bu, br, hist, U, bRHt);
  k_final_mfma<<<dim3(8, 8), 256, 0, stream>>>(bW, bXt, bRHt, bh, U, hist, out);
}